// Round 1
// baseline (217.705 us; speedup 1.0000x reference)
//
#include <hip/hip_runtime.h>
#include <hip/hip_bf16.h>

// MultiHeadGeneticAttention: B=1, T=2048, D=1024, H=16, HD=64, WINDOW=128
// Pipeline:
//   1. convert x,Wg,Wv,Wo fp32->bf16
//   2. G = x@Wg^T+bg (bf16 MFMA GEMM, bf16 out), V = x@Wv^T+bv
//   3. corr kernel: banded g_i.g_j -> c01=(corr+1)/2 stored [H][T][132], denomInv per row
//   4. suminv kernel: per-head sum of 1/denom
//   5. attn_pv: band softmax (logits = c01 * fitness) + PV -> OUT bf16 (T,D)
//   6. out = OUT@Wo^T+bo (MFMA GEMM, fp32 out)

#define T_LEN 2048
#define D_DIM 1024
#define NHEAD 16
#define HD_DIM 64
#define CSTRIDE 132

typedef unsigned short u16;
typedef unsigned int u32;
typedef __bf16 bf16x8 __attribute__((ext_vector_type(8)));
typedef float f32x4 __attribute__((ext_vector_type(4)));

__device__ __forceinline__ float b2f(u32 bits16) { return __uint_as_float(bits16 << 16); }
__device__ __forceinline__ u16 f2b(float f) {
  u32 u = __float_as_uint(f);
  u = (u + 0x7fffu + ((u >> 16) & 1u)) >> 16;
  return (u16)u;
}

// ---------------- convert fp32 -> bf16 (x, Wg, Wv, Wo) ----------------
__global__ __launch_bounds__(256) void convert_kernel(
    const float* __restrict__ x, const float* __restrict__ wg,
    const float* __restrict__ wv, const float* __restrict__ wo,
    u16* __restrict__ xb, u16* __restrict__ wgb,
    u16* __restrict__ wvb, u16* __restrict__ wob) {
  const int c = blockIdx.x * 256 + threadIdx.x;  // one float4 chunk each
  const float* src; u16* dst; int off;
  if (c < 524288)       { src = x;  dst = xb;  off = c; }
  else if (c < 786432)  { src = wg; dst = wgb; off = c - 524288; }
  else if (c < 1048576) { src = wv; dst = wvb; off = c - 786432; }
  else                  { src = wo; dst = wob; off = c - 1048576; }
  const float4 v = reinterpret_cast<const float4*>(src)[off];
  ushort4 o;
  o.x = f2b(v.x); o.y = f2b(v.y); o.z = f2b(v.z); o.w = f2b(v.w);
  reinterpret_cast<ushort4*>(dst)[off] = o;
}

// ---------------- bf16 NT GEMM: C[M,N] = A[M,K] @ Bw[N,K]^T + bias ----------------
template<int OUT_BF16>
__global__ __launch_bounds__(256) void gemm_nt(
    const u16* __restrict__ A, const u16* __restrict__ Bw,
    const float* __restrict__ bias, void* __restrict__ Cout,
    int M, int N, int K) {
  __shared__ __align__(16) u16 As[64 * 72];
  __shared__ __align__(16) u16 Bs[64 * 72];
  const int tid = threadIdx.x;
  const int m0 = blockIdx.y << 6;
  const int n0 = blockIdx.x << 6;
  const int wave = tid >> 6;
  const int lane = tid & 63;
  const int wr = wave >> 1, wc = wave & 1;   // 2x2 waves -> 32x32 per wave
  const int lrow = lane & 15;
  const int kg = lane >> 4;                  // k-group (8 bf16 each)
  f32x4 acc[2][2] = {};
  for (int k0 = 0; k0 < K; k0 += 64) {
#pragma unroll
    for (int p = 0; p < 2; ++p) {
      const int idx = (p << 8) + tid;
      const int row = idx >> 3;
      const int kk = (idx & 7) << 3;
      *reinterpret_cast<uint4*>(&As[row * 72 + kk]) =
          *reinterpret_cast<const uint4*>(&A[(size_t)(m0 + row) * K + k0 + kk]);
      *reinterpret_cast<uint4*>(&Bs[row * 72 + kk]) =
          *reinterpret_cast<const uint4*>(&Bw[(size_t)(n0 + row) * K + k0 + kk]);
    }
    __syncthreads();
#pragma unroll
    for (int kk = 0; kk < 64; kk += 32) {
      const int kf = kk + (kg << 3);
      const bf16x8 a0 = *reinterpret_cast<const bf16x8*>(&As[(wr * 32 + lrow) * 72 + kf]);
      const bf16x8 a1 = *reinterpret_cast<const bf16x8*>(&As[(wr * 32 + 16 + lrow) * 72 + kf]);
      const bf16x8 b0 = *reinterpret_cast<const bf16x8*>(&Bs[(wc * 32 + lrow) * 72 + kf]);
      const bf16x8 b1 = *reinterpret_cast<const bf16x8*>(&Bs[(wc * 32 + 16 + lrow) * 72 + kf]);
      acc[0][0] = __builtin_amdgcn_mfma_f32_16x16x32_bf16(a0, b0, acc[0][0], 0, 0, 0);
      acc[0][1] = __builtin_amdgcn_mfma_f32_16x16x32_bf16(a0, b1, acc[0][1], 0, 0, 0);
      acc[1][0] = __builtin_amdgcn_mfma_f32_16x16x32_bf16(a1, b0, acc[1][0], 0, 0, 0);
      acc[1][1] = __builtin_amdgcn_mfma_f32_16x16x32_bf16(a1, b1, acc[1][1], 0, 0, 0);
    }
    __syncthreads();
  }
#pragma unroll
  for (int mi = 0; mi < 2; ++mi) {
#pragma unroll
    for (int ni = 0; ni < 2; ++ni) {
#pragma unroll
      for (int j = 0; j < 4; ++j) {
        const int row = m0 + wr * 32 + mi * 16 + (kg << 2) + j;
        const int col = n0 + wc * 32 + ni * 16 + lrow;
        const float v = acc[mi][ni][j] + bias[col];
        if (OUT_BF16)
          reinterpret_cast<u16*>(Cout)[(size_t)row * N + col] = f2b(v);
        else
          reinterpret_cast<float*>(Cout)[(size_t)row * N + col] = v;
      }
    }
  }
}

// ---------------- banded correlation kernel ----------------
// grid (T/64, H). Computes c01 for the 129-wide band, row sums -> denomInv.
__global__ __launch_bounds__(256) void corr_kernel(
    const u16* __restrict__ Gb, float* __restrict__ corr01,
    float* __restrict__ denomInv) {
  __shared__ __align__(16) float Gs[192 * 68];
  __shared__ float nrmS[192];
  const int tid = threadIdx.x;
  const int h = blockIdx.y;
  const int i0 = blockIdx.x << 6;
  const int j0 = i0 - 128;
  // stage 192 rows (j0 .. j0+191) of head h, fp32 in LDS
  for (int c = tid; c < 1536; c += 256) {
    const int row = c >> 3;
    const int kk = (c & 7) << 3;
    const int j = j0 + row;
    float4 f0 = {0.f, 0.f, 0.f, 0.f}, f1 = {0.f, 0.f, 0.f, 0.f};
    if (j >= 0) {
      const uint4 raw =
          *reinterpret_cast<const uint4*>(&Gb[((size_t)j << 10) + (h << 6) + kk]);
      f0.x = b2f(raw.x & 0xffffu); f0.y = b2f(raw.x >> 16);
      f0.z = b2f(raw.y & 0xffffu); f0.w = b2f(raw.y >> 16);
      f1.x = b2f(raw.z & 0xffffu); f1.y = b2f(raw.z >> 16);
      f1.z = b2f(raw.w & 0xffffu); f1.w = b2f(raw.w >> 16);
    }
    *reinterpret_cast<float4*>(&Gs[row * 68 + kk]) = f0;
    *reinterpret_cast<float4*>(&Gs[row * 68 + kk + 4]) = f1;
  }
  __syncthreads();
  if (tid < 192) {
    float s = 0.f;
#pragma unroll
    for (int k = 0; k < 64; ++k) { const float g = Gs[tid * 68 + k]; s = fmaf(g, g, s); }
    nrmS[tid] = sqrtf(s);
  }
  __syncthreads();
  const int ty = tid >> 4, tx = tid & 15;
  float acc[4][12];
#pragma unroll
  for (int q = 0; q < 4; ++q)
#pragma unroll
    for (int r = 0; r < 12; ++r) acc[q][r] = 0.f;
  const float* aBase = &Gs[(128 + ty * 4) * 68];
  const float* bBase = &Gs[tx * 68];
  for (int k = 0; k < 64; k += 4) {
    float a_[4][4], b_[12][4];
#pragma unroll
    for (int q = 0; q < 4; ++q)
      *reinterpret_cast<float4*>(a_[q]) = *reinterpret_cast<const float4*>(aBase + q * 68 + k);
#pragma unroll
    for (int r = 0; r < 12; ++r)
      *reinterpret_cast<float4*>(b_[r]) = *reinterpret_cast<const float4*>(bBase + r * 1088 + k);
#pragma unroll
    for (int q = 0; q < 4; ++q)
#pragma unroll
      for (int r = 0; r < 12; ++r)
#pragma unroll
        for (int s = 0; s < 4; ++s)
          acc[q][r] = fmaf(a_[q][s], b_[r][s], acc[q][r]);
  }
#pragma unroll
  for (int q = 0; q < 4; ++q) {
    const int ii = ty * 4 + q;
    const int i = i0 + ii;
    const float nI = nrmS[128 + ii];
    float s = 0.f;
#pragma unroll
    for (int r = 0; r < 12; ++r) {
      const int jl = r * 16 + tx;
      const int joff = ii + 128 - jl;
      if (joff >= 0 && joff <= 128 && joff <= i) {
        const float c01 = 0.5f * (acc[q][r] / (nI * nrmS[jl] + 1e-8f) + 1.0f);
        corr01[(size_t)((h << 11) + i) * CSTRIDE + joff] = c01;
        s += c01;
      }
    }
    s += __shfl_xor(s, 1); s += __shfl_xor(s, 2);
    s += __shfl_xor(s, 4); s += __shfl_xor(s, 8);
    if (tx == 0) {
      const int cnt = (i < 128 ? i : 128) + 1;
      const float gm = (s + 0.5f * (float)(T_LEN - cnt)) * (1.0f / (float)T_LEN);
      denomInv[(h << 11) + i] = 1.0f / (gm + 0.5f);
    }
  }
}

// ---------------- per-head sum of 1/denom ----------------
__global__ __launch_bounds__(256) void suminv_kernel(
    const float* __restrict__ denomInv, float* __restrict__ sumInv) {
  const int h = blockIdx.x;
  float s = 0.f;
  for (int t = threadIdx.x; t < T_LEN; t += 256) s += denomInv[(h << 11) + t];
#pragma unroll
  for (int m = 1; m < 64; m <<= 1) s += __shfl_xor(s, m);
  __shared__ float red[4];
  if ((threadIdx.x & 63) == 0) red[threadIdx.x >> 6] = s;
  __syncthreads();
  if (threadIdx.x == 0) sumInv[h] = red[0] + red[1] + red[2] + red[3];
}

// ---------------- band softmax + PV ----------------
// grid (T/64, H). OUT bf16 layout (T, D) with head h cols [h*64, h*64+64).
__global__ __launch_bounds__(256) void attn_pv_kernel(
    const u16* __restrict__ Vb, const float* __restrict__ corr01,
    const float* __restrict__ denomInv, const float* __restrict__ sumInv,
    u16* __restrict__ Ob) {
  __shared__ __align__(16) float Vs[192 * 68];
  __shared__ __align__(16) float Aw[64 * 196];
  __shared__ float rs[64];
  const int tid = threadIdx.x;
  const int h = blockIdx.y;
  const int i0 = blockIdx.x << 6;
  const int j0 = i0 - 128;
  // stage V rows
  for (int c = tid; c < 1536; c += 256) {
    const int row = c >> 3;
    const int kk = (c & 7) << 3;
    const int j = j0 + row;
    float4 f0 = {0.f, 0.f, 0.f, 0.f}, f1 = {0.f, 0.f, 0.f, 0.f};
    if (j >= 0) {
      const uint4 raw =
          *reinterpret_cast<const uint4*>(&Vb[((size_t)j << 10) + (h << 6) + kk]);
      f0.x = b2f(raw.x & 0xffffu); f0.y = b2f(raw.x >> 16);
      f0.z = b2f(raw.y & 0xffffu); f0.w = b2f(raw.y >> 16);
      f1.x = b2f(raw.z & 0xffffu); f1.y = b2f(raw.z >> 16);
      f1.z = b2f(raw.w & 0xffffu); f1.w = b2f(raw.w >> 16);
    }
    *reinterpret_cast<float4*>(&Vs[row * 68 + kk]) = f0;
    *reinterpret_cast<float4*>(&Vs[row * 68 + kk + 4]) = f1;
  }
  // zero attention weight tile
  for (int c = tid; c < 64 * 196; c += 256) Aw[c] = 0.f;
  __syncthreads();
  // softmax: 4 threads per row
  {
    const int ti = tid >> 2, tq = tid & 3;
    const int i = i0 + ti;
    const int cnt = (i < 128 ? i : 128) + 1;
    const float f = denomInv[(h << 11) + i] / sumInv[h];
    const float* crow = corr01 + (size_t)((h << 11) + i) * CSTRIDE;
    float mx = -1e30f;
    for (int joff = tq; joff < cnt; joff += 4) mx = fmaxf(mx, crow[joff]);
    mx = fmaxf(mx, __shfl_xor(mx, 1));
    mx = fmaxf(mx, __shfl_xor(mx, 2));
    float esum = 0.f;
    for (int joff = tq; joff < cnt; joff += 4) {
      const float w = __expf((crow[joff] - mx) * f);
      esum += w;
      Aw[ti * 196 + (ti + 128 - joff)] = w;
    }
    esum += __shfl_xor(esum, 1);
    esum += __shfl_xor(esum, 2);
    if (tq == 0) rs[ti] = 1.0f / esum;
  }
  __syncthreads();
  // PV: OUT[64 x 64] = Aw[64 x 192] @ Vs[192 x 64]
  const int ty = tid >> 4, tx = tid & 15;
  float acc[4][4];
#pragma unroll
  for (int q = 0; q < 4; ++q)
#pragma unroll
    for (int r = 0; r < 4; ++r) acc[q][r] = 0.f;
  const float* aB = Aw + (ty * 4) * 196;
  const float* bB = Vs + tx * 4;
  for (int k = 0; k < 192; k += 4) {
    float a_[4][4], b_[4][4];
#pragma unroll
    for (int q = 0; q < 4; ++q)
      *reinterpret_cast<float4*>(a_[q]) = *reinterpret_cast<const float4*>(aB + q * 196 + k);
#pragma unroll
    for (int s = 0; s < 4; ++s)
      *reinterpret_cast<float4*>(b_[s]) = *reinterpret_cast<const float4*>(bB + (k + s) * 68);
#pragma unroll
    for (int q = 0; q < 4; ++q)
#pragma unroll
      for (int s = 0; s < 4; ++s)
#pragma unroll
        for (int r = 0; r < 4; ++r)
          acc[q][r] = fmaf(a_[q][s], b_[s][r], acc[q][r]);
  }
#pragma unroll
  for (int q = 0; q < 4; ++q) {
    const float rq = rs[ty * 4 + q];
    const size_t base = ((size_t)(i0 + ty * 4 + q) << 10) + (h << 6) + tx * 4;
    ushort4 o;
    o.x = f2b(acc[q][0] * rq); o.y = f2b(acc[q][1] * rq);
    o.z = f2b(acc[q][2] * rq); o.w = f2b(acc[q][3] * rq);
    *reinterpret_cast<ushort4*>(&Ob[base]) = o;
  }
}

extern "C" void kernel_launch(void* const* d_in, const int* in_sizes, int n_in,
                              void* d_out, int out_size, void* d_ws, size_t ws_size,
                              hipStream_t stream) {
  const float* x  = (const float*)d_in[0];
  const float* Wg = (const float*)d_in[1];
  const float* bg = (const float*)d_in[2];
  const float* Wv = (const float*)d_in[3];
  const float* bv = (const float*)d_in[4];
  const float* Wo = (const float*)d_in[5];
  const float* bo = (const float*)d_in[6];
  float* out = (float*)d_out;
  char* ws = (char*)d_ws;

  u16* xb   = (u16*)(ws);                        // 4 MB
  u16* wgb  = (u16*)(ws + ((size_t)4 << 20));    // 2 MB
  u16* wvb  = (u16*)(ws + ((size_t)6 << 20));    // 2 MB
  u16* wob  = (u16*)(ws + ((size_t)8 << 20));    // 2 MB
  u16* Gbv  = (u16*)(ws + ((size_t)10 << 20));   // 4 MB
  u16* Vbv  = (u16*)(ws + ((size_t)14 << 20));   // 4 MB
  u16* Ob   = (u16*)(ws + ((size_t)18 << 20));   // 4 MB
  float* corr01   = (float*)(ws + ((size_t)22 << 20));              // 17,301,504 B
  float* denomInv = (float*)(ws + ((size_t)22 << 20) + 17301504);   // 131,072 B
  float* sumInv   = denomInv + NHEAD * T_LEN;                       // 64 B

  convert_kernel<<<5120, 256, 0, stream>>>(x, Wg, Wv, Wo, xb, wgb, wvb, wob);
  gemm_nt<1><<<dim3(16, 32), 256, 0, stream>>>(xb, wgb, bg, Gbv, T_LEN, D_DIM, D_DIM);
  gemm_nt<1><<<dim3(16, 32), 256, 0, stream>>>(xb, wvb, bv, Vbv, T_LEN, D_DIM, D_DIM);
  corr_kernel<<<dim3(32, 16), 256, 0, stream>>>(Gbv, corr01, denomInv);
  suminv_kernel<<<16, 256, 0, stream>>>(denomInv, sumInv);
  attn_pv_kernel<<<dim3(32, 16), 256, 0, stream>>>(Vbv, corr01, denomInv, sumInv, Ob);
  gemm_nt<0><<<dim3(16, 32), 256, 0, stream>>>(Ob, wob, bo, out, T_LEN, D_DIM, D_DIM);
}

// Round 2
// 176.082 us; speedup vs baseline: 1.2364x; 1.2364x over previous
//
#include <hip/hip_runtime.h>
#include <hip/hip_bf16.h>

// MultiHeadGeneticAttention — algebraic collapse.
// fitness = 1/(denom*sum_inv) <= 5.2e-4 (hard bound), so softmax logits span
// <= 5.2e-4 -> attention is uniform over the causal 129-window to ~5e-4
// relative; output deviation ~1e-5, far below the bf16 noise floor (0.0156
// observed) and threshold (0.0722). Uniform banded mean M is head-independent
// and commutes: out = M·x·(Wo·Wv)^T + (Wo·bv + bo). Wg/bg unused.
//
// Pipeline:
//   prep:     Wo->bf16, WvT->bf16 (transpose), bias2 = Wo@bv + bo
//   gemm W2:  W2[d][k] = sum_e Wo[d,e]*Wv[e,k]  (NT: A=Wo_b, B=WvT_b), bf16
//   bandmean: xm[i] = mean_{j in [max(0,i-128), i]} x[j]  (fp32, ->bf16)
//   gemm out: out = xm @ W2^T + bias2  (fp32)

typedef unsigned short u16;
typedef unsigned int u32;
typedef __bf16 bf16x8 __attribute__((ext_vector_type(8)));
typedef float f32x4 __attribute__((ext_vector_type(4)));

__device__ __forceinline__ u16 f2b(float f) {
  u32 u = __float_as_uint(f);
  u = (u + 0x7fffu + ((u >> 16) & 1u)) >> 16;
  return (u16)u;
}

// ---------------- prep: convert Wo, transpose Wv, bias2 ----------------
__global__ __launch_bounds__(256) void prep_kernel(
    const float* __restrict__ Wv, const float* __restrict__ Wo,
    const float* __restrict__ bv, const float* __restrict__ bo,
    u16* __restrict__ wob, u16* __restrict__ wvT, float* __restrict__ bias2) {
  const int b = blockIdx.x, t = threadIdx.x;
  __shared__ float L[32][33];
  if (b < 1024) {
    // Wo fp32 -> bf16, 1024 els per block
    const int c = (b << 8) + t;
    const float4 v = reinterpret_cast<const float4*>(Wo)[c];
    ushort4 o;
    o.x = f2b(v.x); o.y = f2b(v.y); o.z = f2b(v.z); o.w = f2b(v.w);
    reinterpret_cast<ushort4*>(wob)[c] = o;
  } else if (b < 2048) {
    // 32x32 tile transpose of Wv, bf16 out
    const int bb = b - 1024;
    const int r0 = (bb >> 5) << 5, c0 = (bb & 31) << 5;
    const int tx = t & 31, ty = t >> 5;  // ty 0..7
#pragma unroll
    for (int r = 0; r < 4; ++r)
      L[ty + (r << 3)][tx] = Wv[(size_t)(r0 + ty + (r << 3)) * 1024 + c0 + tx];
    __syncthreads();
#pragma unroll
    for (int r = 0; r < 4; ++r)
      wvT[(size_t)(c0 + ty + (r << 3)) * 1024 + r0 + tx] = f2b(L[tx][ty + (r << 3)]);
  } else {
    // bias2[d] = bo[d] + sum_e Wo[d,e]*bv[e]   (fp32, exact path)
    const int d = ((b - 2048) << 8) + t;
    float a0 = bo[d], a1 = 0.f, a2 = 0.f, a3 = 0.f;
    for (int e = 0; e < 1024; e += 4) {
      const float4 w = *reinterpret_cast<const float4*>(&Wo[(size_t)d * 1024 + e]);
      const float4 c = *reinterpret_cast<const float4*>(&bv[e]);
      a0 += w.x * c.x; a1 += w.y * c.y; a2 += w.z * c.z; a3 += w.w * c.w;
    }
    bias2[d] = (a0 + a1) + (a2 + a3);
  }
}

// ---------------- band mean: xm[i][d] = mean of x rows [i-128, i] ----------------
// grid (T/256, D/32): 256-row i-blocks x 32-col d-blocks; running-sum per column.
__global__ __launch_bounds__(256) void bandmean_kernel(
    const float* __restrict__ x, u16* __restrict__ xm) {
  __shared__ float L[384 * 32];
  const int t = threadIdx.x;
  const int i0 = blockIdx.x << 8;
  const int db = blockIdx.y << 5;
  const int j0 = i0 - 128;
  // stage 384 rows x 32 cols fp32 (zero for j<0)
  for (int c = t; c < 3072; c += 256) {
    const int row = c >> 3, d0 = (c & 7) << 2;
    const int j = j0 + row;
    float4 v = {0.f, 0.f, 0.f, 0.f};
    if (j >= 0) v = *reinterpret_cast<const float4*>(&x[(size_t)j * 1024 + db + d0]);
    *reinterpret_cast<float4*>(&L[row * 32 + d0]) = v;
  }
  __syncthreads();
  const int d = t & 31, seg = t >> 5;  // 8 segments of 32 rows
  const int il0 = seg << 5;
  // base sum over rows [il0, il0+128]  (j in [i-128, i] for i = i0+il0)
  float s0 = 0.f, s1 = 0.f, s2 = 0.f, s3 = 0.f;
  for (int r = il0; r < il0 + 128; r += 4) {
    s0 += L[(r + 0) * 32 + d];
    s1 += L[(r + 1) * 32 + d];
    s2 += L[(r + 2) * 32 + d];
    s3 += L[(r + 3) * 32 + d];
  }
  float S = (s0 + s1) + (s2 + s3) + L[(il0 + 128) * 32 + d];
  for (int s = 0; s < 32; ++s) {
    const int i = i0 + il0 + s;
    const int cnt = (i < 128 ? i : 128) + 1;
    xm[(size_t)i * 1024 + db + d] = f2b(S / (float)cnt);
    if (s < 31) S += L[(il0 + s + 129) * 32 + d] - L[(il0 + s) * 32 + d];
  }
}

// ---------------- bf16 NT GEMM: C[M,N] = A[M,K] @ Bw[N,K]^T (+bias) ----------------
// Tile 64x128, BK=64, 4 waves (2x2, wave tile 32x64), reg-staged double buffer,
// one barrier per K-step (T14 async-split: loads issued before MFMA, LDS-write after).
template<int OUT_F32, int HAS_BIAS>
__global__ __launch_bounds__(256) void gemm_nt(
    const u16* __restrict__ A, const u16* __restrict__ Bw,
    const float* __restrict__ bias, void* __restrict__ Cout,
    const int M, const int N, const int K) {
  __shared__ __align__(16) u16 As[2][64 * 72];
  __shared__ __align__(16) u16 Bs[2][128 * 72];
  const int tid = threadIdx.x;
  const int m0 = blockIdx.y << 6;
  const int n0 = blockIdx.x << 7;
  const int wv = tid >> 6, l = tid & 63;
  const int wr = wv >> 1, wc = wv & 1;
  const int lrow = l & 15, kg = l >> 4;

  uint4 rA[2], rB[4];
  f32x4 acc[2][4] = {};

  // prologue: stage k0=0
#pragma unroll
  for (int p = 0; p < 2; ++p) {
    const int idx = (p << 8) + tid;
    rA[p] = *reinterpret_cast<const uint4*>(&A[(size_t)(m0 + (idx >> 3)) * K + ((idx & 7) << 3)]);
  }
#pragma unroll
  for (int p = 0; p < 4; ++p) {
    const int idx = (p << 8) + tid;
    rB[p] = *reinterpret_cast<const uint4*>(&Bw[(size_t)(n0 + (idx >> 3)) * K + ((idx & 7) << 3)]);
  }
#pragma unroll
  for (int p = 0; p < 2; ++p) {
    const int idx = (p << 8) + tid;
    *reinterpret_cast<uint4*>(&As[0][(idx >> 3) * 72 + ((idx & 7) << 3)]) = rA[p];
  }
#pragma unroll
  for (int p = 0; p < 4; ++p) {
    const int idx = (p << 8) + tid;
    *reinterpret_cast<uint4*>(&Bs[0][(idx >> 3) * 72 + ((idx & 7) << 3)]) = rB[p];
  }
  __syncthreads();

  const int NT = K >> 6;
  int cur = 0;
  for (int tst = 0; tst < NT; ++tst) {
    if (tst + 1 < NT) {
      const int k0 = (tst + 1) << 6;
#pragma unroll
      for (int p = 0; p < 2; ++p) {
        const int idx = (p << 8) + tid;
        rA[p] = *reinterpret_cast<const uint4*>(&A[(size_t)(m0 + (idx >> 3)) * K + k0 + ((idx & 7) << 3)]);
      }
#pragma unroll
      for (int p = 0; p < 4; ++p) {
        const int idx = (p << 8) + tid;
        rB[p] = *reinterpret_cast<const uint4*>(&Bw[(size_t)(n0 + (idx >> 3)) * K + k0 + ((idx & 7) << 3)]);
      }
    }
#pragma unroll
    for (int kk = 0; kk < 64; kk += 32) {
      const int kf = kk + (kg << 3);
      const bf16x8 a0 = *reinterpret_cast<const bf16x8*>(&As[cur][(wr * 32 + lrow) * 72 + kf]);
      const bf16x8 a1 = *reinterpret_cast<const bf16x8*>(&As[cur][(wr * 32 + 16 + lrow) * 72 + kf]);
      const bf16x8 b0 = *reinterpret_cast<const bf16x8*>(&Bs[cur][(wc * 64 + lrow) * 72 + kf]);
      const bf16x8 b1 = *reinterpret_cast<const bf16x8*>(&Bs[cur][(wc * 64 + 16 + lrow) * 72 + kf]);
      const bf16x8 b2 = *reinterpret_cast<const bf16x8*>(&Bs[cur][(wc * 64 + 32 + lrow) * 72 + kf]);
      const bf16x8 b3 = *reinterpret_cast<const bf16x8*>(&Bs[cur][(wc * 64 + 48 + lrow) * 72 + kf]);
      acc[0][0] = __builtin_amdgcn_mfma_f32_16x16x32_bf16(a0, b0, acc[0][0], 0, 0, 0);
      acc[0][1] = __builtin_amdgcn_mfma_f32_16x16x32_bf16(a0, b1, acc[0][1], 0, 0, 0);
      acc[0][2] = __builtin_amdgcn_mfma_f32_16x16x32_bf16(a0, b2, acc[0][2], 0, 0, 0);
      acc[0][3] = __builtin_amdgcn_mfma_f32_16x16x32_bf16(a0, b3, acc[0][3], 0, 0, 0);
      acc[1][0] = __builtin_amdgcn_mfma_f32_16x16x32_bf16(a1, b0, acc[1][0], 0, 0, 0);
      acc[1][1] = __builtin_amdgcn_mfma_f32_16x16x32_bf16(a1, b1, acc[1][1], 0, 0, 0);
      acc[1][2] = __builtin_amdgcn_mfma_f32_16x16x32_bf16(a1, b2, acc[1][2], 0, 0, 0);
      acc[1][3] = __builtin_amdgcn_mfma_f32_16x16x32_bf16(a1, b3, acc[1][3], 0, 0, 0);
    }
    if (tst + 1 < NT) {
#pragma unroll
      for (int p = 0; p < 2; ++p) {
        const int idx = (p << 8) + tid;
        *reinterpret_cast<uint4*>(&As[cur ^ 1][(idx >> 3) * 72 + ((idx & 7) << 3)]) = rA[p];
      }
#pragma unroll
      for (int p = 0; p < 4; ++p) {
        const int idx = (p << 8) + tid;
        *reinterpret_cast<uint4*>(&Bs[cur ^ 1][(idx >> 3) * 72 + ((idx & 7) << 3)]) = rB[p];
      }
      __syncthreads();
      cur ^= 1;
    }
  }

  // epilogue
#pragma unroll
  for (int mi = 0; mi < 2; ++mi) {
#pragma unroll
    for (int ni = 0; ni < 4; ++ni) {
#pragma unroll
      for (int j = 0; j < 4; ++j) {
        const int row = m0 + wr * 32 + mi * 16 + (kg << 2) + j;
        const int col = n0 + wc * 64 + ni * 16 + lrow;
        float v = acc[mi][ni][j];
        if (HAS_BIAS) v += bias[col];
        if (OUT_F32)
          reinterpret_cast<float*>(Cout)[(size_t)row * N + col] = v;
        else
          reinterpret_cast<u16*>(Cout)[(size_t)row * N + col] = f2b(v);
      }
    }
  }
}

extern "C" void kernel_launch(void* const* d_in, const int* in_sizes, int n_in,
                              void* d_out, int out_size, void* d_ws, size_t ws_size,
                              hipStream_t stream) {
  const float* x  = (const float*)d_in[0];
  const float* Wv = (const float*)d_in[3];
  const float* bv = (const float*)d_in[4];
  const float* Wo = (const float*)d_in[5];
  const float* bo = (const float*)d_in[6];
  float* out = (float*)d_out;
  char* ws = (char*)d_ws;

  u16* wob   = (u16*)(ws);                          // 2 MB
  u16* wvT   = (u16*)(ws + ((size_t)2 << 20));      // 2 MB
  u16* W2    = (u16*)(ws + ((size_t)4 << 20));      // 2 MB
  u16* xm    = (u16*)(ws + ((size_t)6 << 20));      // 4 MB
  float* bias2 = (float*)(ws + ((size_t)10 << 20)); // 4 KB

  prep_kernel<<<2052, 256, 0, stream>>>(Wv, Wo, bv, bo, wob, wvT, bias2);
  // W2[d][k] = sum_e Wo[d,e] Wv[e,k] : NT with A=Wo_b [d][e], B=WvT [k][e]
  gemm_nt<0, 0><<<dim3(8, 16), 256, 0, stream>>>(wob, wvT, nullptr, W2, 1024, 1024, 1024);
  bandmean_kernel<<<dim3(8, 32), 256, 0, stream>>>(x, xm);
  // out = xm @ W2^T + bias2
  gemm_nt<1, 1><<<dim3(8, 32), 256, 0, stream>>>(xm, W2, bias2, out, 2048, 1024, 1024);
}

// Round 3
// 171.669 us; speedup vs baseline: 1.2682x; 1.0257x over previous
//
#include <hip/hip_runtime.h>
#include <hip/hip_bf16.h>

// MultiHeadGeneticAttention — algebraic collapse (validated round 2: absmax
// 0.0156 identical to full-pipeline round 1 -> softmax-uniformity is exact to
// bf16 noise).  out = bandmean(x) @ (Wo·Wv)^T + (Wo·bv + bo).
//
// Round 3: 3 graph nodes; GEMMs rebuilt latency-first:
//   64x64 tile, BK=64, 2-deep register prefetch (counted vmcnt via per-reg
//   deps), XOR-swizzled LDS (2-way max bank aliasing), 1 barrier/K-step.

typedef unsigned short u16;
typedef unsigned int u32;
typedef __bf16 bf16x8 __attribute__((ext_vector_type(8)));
typedef float f32x4 __attribute__((ext_vector_type(4)));

__device__ __forceinline__ u16 f2b(float f) {
  u32 u = __float_as_uint(f);
  u = (u + 0x7fffu + ((u >> 16) & 1u)) >> 16;
  return (u16)u;
}

// ---------------- kernel A: bandmean + bias2 + convert Wo + transpose Wv ----
// blocks [0,256): bandmean   [256,260): bias2
// blocks [260,1284): Wo->bf16   [1284,2308): Wv^T->bf16
__global__ __launch_bounds__(256) void prep_kernel(
    const float* __restrict__ x, const float* __restrict__ Wv,
    const float* __restrict__ Wo, const float* __restrict__ bv,
    const float* __restrict__ bo, u16* __restrict__ xm,
    u16* __restrict__ wob, u16* __restrict__ wvT, float* __restrict__ bias2) {
  __shared__ float LB[384 * 32];
  const int b = blockIdx.x, t = threadIdx.x;
  if (b < 256) {
    // bandmean: xm[i][d] = mean_{j in [i-128, i]} x[j][d], 256 i x 32 d per blk
    const int i0 = (b >> 5) << 8;       // 8 i-panels
    const int db = (b & 31) << 5;       // 32 d-panels
    const int j0 = i0 - 128;
    for (int c = t; c < 3072; c += 256) {
      const int row = c >> 3, d0 = (c & 7) << 2;
      const int j = j0 + row;
      float4 v = {0.f, 0.f, 0.f, 0.f};
      if (j >= 0) v = *reinterpret_cast<const float4*>(&x[(size_t)j * 1024 + db + d0]);
      *reinterpret_cast<float4*>(&LB[row * 32 + d0]) = v;
    }
    __syncthreads();
    const int d = t & 31, seg = t >> 5;
    const int il0 = seg << 5;
    float s0 = 0.f, s1 = 0.f, s2 = 0.f, s3 = 0.f;
    for (int r = il0; r < il0 + 128; r += 4) {
      s0 += LB[(r + 0) * 32 + d];
      s1 += LB[(r + 1) * 32 + d];
      s2 += LB[(r + 2) * 32 + d];
      s3 += LB[(r + 3) * 32 + d];
    }
    float S = (s0 + s1) + (s2 + s3) + LB[(il0 + 128) * 32 + d];
    for (int s = 0; s < 32; ++s) {
      const int i = i0 + il0 + s;
      const int cnt = (i < 128 ? i : 128) + 1;
      xm[(size_t)i * 1024 + db + d] = f2b(S / (float)cnt);
      if (s < 31) S += LB[(il0 + s + 129) * 32 + d] - LB[(il0 + s) * 32 + d];
    }
  } else if (b < 260) {
    // bias2[d] = bo[d] + Wo[d,:]·bv  (fp32 exact)
    const int d = ((b - 256) << 8) + t;
    float a0 = bo[d], a1 = 0.f, a2 = 0.f, a3 = 0.f;
    for (int e = 0; e < 1024; e += 4) {
      const float4 w = *reinterpret_cast<const float4*>(&Wo[(size_t)d * 1024 + e]);
      const float4 c = *reinterpret_cast<const float4*>(&bv[e]);
      a0 += w.x * c.x; a1 += w.y * c.y; a2 += w.z * c.z; a3 += w.w * c.w;
    }
    bias2[d] = (a0 + a1) + (a2 + a3);
  } else if (b < 1284) {
    // Wo fp32 -> bf16
    const int c = ((b - 260) << 8) + t;
    const float4 v = reinterpret_cast<const float4*>(Wo)[c];
    ushort4 o;
    o.x = f2b(v.x); o.y = f2b(v.y); o.z = f2b(v.z); o.w = f2b(v.w);
    reinterpret_cast<ushort4*>(wob)[c] = o;
  } else {
    // 32x32 tile transpose of Wv -> bf16
    float (*L)[33] = reinterpret_cast<float(*)[33]>(LB);
    const int bb = b - 1284;
    const int r0 = (bb >> 5) << 5, c0 = (bb & 31) << 5;
    const int tx = t & 31, ty = t >> 5;  // ty 0..7
#pragma unroll
    for (int r = 0; r < 4; ++r)
      L[ty + (r << 3)][tx] = Wv[(size_t)(r0 + ty + (r << 3)) * 1024 + c0 + tx];
    __syncthreads();
#pragma unroll
    for (int r = 0; r < 4; ++r)
      wvT[(size_t)(c0 + ty + (r << 3)) * 1024 + r0 + tx] = f2b(L[tx][ty + (r << 3)]);
  }
}

// ---------------- bf16 NT GEMM: C[M,N] = A[M,K] @ Bw[N,K]^T (+bias) ----------
// 64x64 tile, 4 waves (2x2, 32x32 each), BK=64, XOR-swizzled LDS,
// 2-deep register prefetch, 1 barrier per K-step.
#define MFMA_BF16 __builtin_amdgcn_mfma_f32_16x16x32_bf16
template<int OUT_F32, int HAS_BIAS>
__global__ __launch_bounds__(256) void gemm_nt(
    const u16* __restrict__ A, const u16* __restrict__ Bw,
    const float* __restrict__ bias, void* __restrict__ Cout,
    const int M, const int N, const int K) {
  __shared__ __align__(16) u16 As[2][64 * 64];
  __shared__ __align__(16) u16 Bs[2][64 * 64];
  const int tid = threadIdx.x;
  const int m0 = blockIdx.y << 6, n0 = blockIdx.x << 6;
  const int wv = tid >> 6, l = tid & 63;
  const int wr = wv >> 1, wc = wv & 1;
  const int lrow = l & 15, kg = l >> 4;
  // loader geometry: idx=(p<<8)+tid -> row=idx>>3 (0..63), col-group cg=idx&7
  const int lr0 = tid >> 3, lcg = tid & 7;
  const size_t gA0 = (size_t)(m0 + lr0) * K + (lcg << 3);
  const size_t gA1 = (size_t)(m0 + 32 + lr0) * K + (lcg << 3);
  const size_t gB0 = (size_t)(n0 + lr0) * K + (lcg << 3);
  const size_t gB1 = (size_t)(n0 + 32 + lr0) * K + (lcg << 3);
  const int sw0 = (lr0 << 6) + (((lcg ^ (lr0 & 7))) << 3);
  const int sw1 = ((lr0 + 32) << 6) + (((lcg ^ (lr0 & 7))) << 3);
  const int swm = (lrow & 7);

  uint4 ra0[2], rb0[2], ra1[2], rb1[2];
  f32x4 acc[2][2] = {};

#define GLOAD(k0, ra_, rb_)                                              \
  do {                                                                   \
    ra_[0] = *reinterpret_cast<const uint4*>(&A[gA0 + (k0)]);            \
    ra_[1] = *reinterpret_cast<const uint4*>(&A[gA1 + (k0)]);            \
    rb_[0] = *reinterpret_cast<const uint4*>(&Bw[gB0 + (k0)]);           \
    rb_[1] = *reinterpret_cast<const uint4*>(&Bw[gB1 + (k0)]);           \
  } while (0)
#define LWRITE(buf, ra_, rb_)                                            \
  do {                                                                   \
    *reinterpret_cast<uint4*>(&As[buf][sw0]) = ra_[0];                   \
    *reinterpret_cast<uint4*>(&As[buf][sw1]) = ra_[1];                   \
    *reinterpret_cast<uint4*>(&Bs[buf][sw0]) = rb_[0];                   \
    *reinterpret_cast<uint4*>(&Bs[buf][sw1]) = rb_[1];                   \
  } while (0)
#define DOMFMA(buf)                                                      \
  do {                                                                   \
    _Pragma("unroll")                                                    \
    for (int kk = 0; kk < 64; kk += 32) {                                \
      const int g = (kk >> 3) + kg;                                      \
      const int swa = ((g ^ swm) << 3);                                  \
      const bf16x8 a0 = *reinterpret_cast<const bf16x8*>(                \
          &As[buf][((wr * 32 + lrow) << 6) + swa]);                      \
      const bf16x8 a1 = *reinterpret_cast<const bf16x8*>(                \
          &As[buf][((wr * 32 + 16 + lrow) << 6) + swa]);                 \
      const bf16x8 b0 = *reinterpret_cast<const bf16x8*>(                \
          &Bs[buf][((wc * 32 + lrow) << 6) + swa]);                      \
      const bf16x8 b1 = *reinterpret_cast<const bf16x8*>(                \
          &Bs[buf][((wc * 32 + 16 + lrow) << 6) + swa]);                 \
      acc[0][0] = MFMA_BF16(a0, b0, acc[0][0], 0, 0, 0);                 \
      acc[0][1] = MFMA_BF16(a0, b1, acc[0][1], 0, 0, 0);                 \
      acc[1][0] = MFMA_BF16(a1, b0, acc[1][0], 0, 0, 0);                 \
      acc[1][1] = MFMA_BF16(a1, b1, acc[1][1], 0, 0, 0);                 \
    }                                                                    \
  } while (0)

  const int NT = K >> 6;  // >= 2, even
  GLOAD(0, ra0, rb0);
  GLOAD(64, ra1, rb1);
  LWRITE(0, ra0, rb0);
  __syncthreads();
  int cur = 0;
  for (int t = 0; t < NT; t += 2) {
    // sub-iter t: LDS[cur]=tile t; set1 holds tile t+1; set0 free
    if (t + 2 < NT) GLOAD((size_t)(t + 2) << 6, ra0, rb0);
    DOMFMA(cur);
    if (t + 1 < NT) LWRITE(cur ^ 1, ra1, rb1);
    __syncthreads();
    cur ^= 1;
    // sub-iter t+1: LDS[cur]=tile t+1; set0 holds tile t+2; set1 free
    if (t + 1 < NT) {
      if (t + 3 < NT) GLOAD((size_t)(t + 3) << 6, ra1, rb1);
      DOMFMA(cur);
      if (t + 2 < NT) LWRITE(cur ^ 1, ra0, rb0);
      __syncthreads();
      cur ^= 1;
    }
  }

  // epilogue
#pragma unroll
  for (int mi = 0; mi < 2; ++mi) {
#pragma unroll
    for (int ni = 0; ni < 2; ++ni) {
#pragma unroll
      for (int j = 0; j < 4; ++j) {
        const int row = m0 + wr * 32 + mi * 16 + (kg << 2) + j;
        const int col = n0 + wc * 32 + ni * 16 + lrow;
        float v = acc[mi][ni][j];
        if (HAS_BIAS) v += bias[col];
        if (OUT_F32)
          reinterpret_cast<float*>(Cout)[(size_t)row * N + col] = v;
        else
          reinterpret_cast<u16*>(Cout)[(size_t)row * N + col] = f2b(v);
      }
    }
  }
#undef GLOAD
#undef LWRITE
#undef DOMFMA
}

extern "C" void kernel_launch(void* const* d_in, const int* in_sizes, int n_in,
                              void* d_out, int out_size, void* d_ws, size_t ws_size,
                              hipStream_t stream) {
  const float* x  = (const float*)d_in[0];
  const float* Wv = (const float*)d_in[3];
  const float* bv = (const float*)d_in[4];
  const float* Wo = (const float*)d_in[5];
  const float* bo = (const float*)d_in[6];
  float* out = (float*)d_out;
  char* ws = (char*)d_ws;

  u16* wob   = (u16*)(ws);                          // 2 MB
  u16* wvT   = (u16*)(ws + ((size_t)2 << 20));      // 2 MB
  u16* W2    = (u16*)(ws + ((size_t)4 << 20));      // 2 MB
  u16* xm    = (u16*)(ws + ((size_t)6 << 20));      // 4 MB
  float* bias2 = (float*)(ws + ((size_t)10 << 20)); // 4 KB

  prep_kernel<<<2308, 256, 0, stream>>>(x, Wv, Wo, bv, bo, xm, wob, wvT, bias2);
  // W2[d][k] = sum_e Wo[d,e] Wv[e,k]  (NT form: A=wob [d][e], B=wvT [k][e])
  gemm_nt<0, 0><<<dim3(16, 16), 256, 0, stream>>>(wob, wvT, nullptr, W2, 1024, 1024, 1024);
  // out = xm @ W2^T + bias2
  gemm_nt<1, 1><<<dim3(16, 32), 256, 0, stream>>>(xm, W2, bias2, out, 2048, 1024, 1024);
}